// Round 1
// baseline (291.343 us; speedup 1.0000x reference)
//
#include <hip/hip_runtime.h>
#include <stdint.h>

// ---------- constants for this problem ----------
#define NNODES 50000
#define NEDGES 800000
#define NFEAT  128
#define NREL   3

// ---------- helpers ----------
__device__ __forceinline__ uint32_t f2bf(float x) {
    uint32_t u = __builtin_bit_cast(uint32_t, x);
    // round-to-nearest-even
    uint32_t r = (u + 0x7FFFu + ((u >> 16) & 1u)) >> 16;
    return r & 0xFFFFu;
}
__device__ __forceinline__ float bf2f(uint32_t b) {
    uint32_t u = b << 16;
    return __builtin_bit_cast(float, u);
}

// ---------- K0: zero the histogram counters ----------
__global__ void k_zero(int* __restrict__ p, int n) {
    int i = blockIdx.x * 256 + threadIdx.x;
    if (i < n) p[i] = 0;
}

// ---------- K1: grouped GEMM  hr[r] = feat @ W[r], stored bf16 ----------
// grid (ceil(N/64), 3), block 256 (16x16), BM=64, BN=128, BK=64 (2 chunks)
__global__ __launch_bounds__(256) void k_gemm(
    const float* __restrict__ feat, const float* __restrict__ W,
    uint16_t* __restrict__ hr, int N)
{
    __shared__ float fl[64][72];    // feat tile [row][k], padded
    __shared__ float wl[64][128];   // W tile [k][col]

    const int rb = blockIdx.y;
    const int n0 = blockIdx.x * 64;
    const int t  = threadIdx.x;
    const int tx = t & 15;          // col group: 8 cols each
    const int ty = t >> 4;          // row group: 4 rows each

    float acc[4][8];
    #pragma unroll
    for (int i = 0; i < 4; i++)
        #pragma unroll
        for (int j = 0; j < 8; j++) acc[i][j] = 0.f;

    const float* Wr = W + (size_t)rb * NFEAT * NFEAT;

    for (int k0 = 0; k0 < NFEAT; k0 += 64) {
        // stage feature tile: rows n0..n0+63, k = k0..k0+63
        {
            const int kq  = t & 15;   // float4 index along k
            const int row = t >> 4;   // 16 rows per pass
            #pragma unroll
            for (int rr = row; rr < 64; rr += 16) {
                const int n = n0 + rr;
                float4 v = make_float4(0.f, 0.f, 0.f, 0.f);
                if (n < N)
                    v = *reinterpret_cast<const float4*>(&feat[(size_t)n * NFEAT + k0 + kq * 4]);
                *reinterpret_cast<float4*>(&fl[rr][kq * 4]) = v;
            }
            // stage W tile: k rows k0..k0+63, all 128 cols
            const int c4 = t & 31;
            const int kk = t >> 5;
            #pragma unroll
            for (int k = kk; k < 64; k += 8) {
                float4 v = *reinterpret_cast<const float4*>(&Wr[(size_t)(k0 + k) * NFEAT + c4 * 4]);
                *reinterpret_cast<float4*>(&wl[k][c4 * 4]) = v;
            }
        }
        __syncthreads();

        const int mr = ty * 4;
        const int mc = tx * 8;
        for (int k = 0; k < 64; k++) {
            float a0 = fl[mr + 0][k], a1 = fl[mr + 1][k], a2 = fl[mr + 2][k], a3 = fl[mr + 3][k];
            float4 b0 = *reinterpret_cast<const float4*>(&wl[k][mc]);
            float4 b1 = *reinterpret_cast<const float4*>(&wl[k][mc + 4]);
            float a[4] = {a0, a1, a2, a3};
            float b[8] = {b0.x, b0.y, b0.z, b0.w, b1.x, b1.y, b1.z, b1.w};
            #pragma unroll
            for (int i = 0; i < 4; i++)
                #pragma unroll
                for (int j = 0; j < 8; j++) acc[i][j] += a[i] * b[j];
        }
        __syncthreads();
    }

    // epilogue: convert to bf16, 16B stores
    const int mr = ty * 4;
    const int mc = tx * 8;
    #pragma unroll
    for (int i = 0; i < 4; i++) {
        const int n = n0 + mr + i;
        if (n < N) {
            uint4 pk;
            pk.x = f2bf(acc[i][0]) | (f2bf(acc[i][1]) << 16);
            pk.y = f2bf(acc[i][2]) | (f2bf(acc[i][3]) << 16);
            pk.z = f2bf(acc[i][4]) | (f2bf(acc[i][5]) << 16);
            pk.w = f2bf(acc[i][6]) | (f2bf(acc[i][7]) << 16);
            *reinterpret_cast<uint4*>(&hr[((size_t)rb * N + n) * NFEAT + mc]) = pk;
        }
    }
}

// ---------- K2: histogram of dst ----------
__global__ void k_hist(const int* __restrict__ dst, int* __restrict__ counts, int E) {
    int e = blockIdx.x * 256 + threadIdx.x;
    if (e < E) atomicAdd(&counts[dst[e]], 1);
}

// ---------- K3: per-block reduce of counts ----------
__global__ void k_block_reduce(const int* __restrict__ counts, int* __restrict__ blocksum, int n) {
    __shared__ int sm[256];
    int t = threadIdx.x;
    int i = blockIdx.x * 256 + t;
    sm[t] = (i < n) ? counts[i] : 0;
    __syncthreads();
    for (int s = 128; s > 0; s >>= 1) {
        if (t < s) sm[t] += sm[t + s];
        __syncthreads();
    }
    if (t == 0) blocksum[blockIdx.x] = sm[0];
}

// ---------- K4: single-block exclusive scan of block sums ----------
__global__ void k_scan_partials(const int* __restrict__ blocksum, int* __restrict__ blockoff, int nb) {
    __shared__ int sm[256];
    int t = threadIdx.x;
    int v = (t < nb) ? blocksum[t] : 0;
    sm[t] = v;
    __syncthreads();
    for (int s = 1; s < 256; s <<= 1) {
        int add = (t >= s) ? sm[t - s] : 0;
        __syncthreads();
        sm[t] += add;
        __syncthreads();
    }
    if (t < nb) blockoff[t] = sm[t] - v;
}

// ---------- K5: write offsets (exclusive scan) + cursor copy ----------
__global__ void k_offsets(const int* __restrict__ counts, const int* __restrict__ blockoff,
                          int* __restrict__ offsets, int* __restrict__ cursor, int n, int total) {
    __shared__ int sm[256];
    int t = threadIdx.x;
    int i = blockIdx.x * 256 + t;
    int v = (i < n) ? counts[i] : 0;
    sm[t] = v;
    __syncthreads();
    for (int s = 1; s < 256; s <<= 1) {
        int add = (t >= s) ? sm[t - s] : 0;
        __syncthreads();
        sm[t] += add;
        __syncthreads();
    }
    int excl = sm[t] - v + blockoff[blockIdx.x];
    if (i < n) { offsets[i] = excl; cursor[i] = excl; }
    if (i == 0) offsets[n] = total;
}

// ---------- K6: fill CSR edge lists ----------
__global__ void k_fill(const int* __restrict__ dst, int* __restrict__ cursor,
                       int* __restrict__ edge_ids, int E) {
    int e = blockIdx.x * 256 + threadIdx.x;
    if (e < E) {
        int p = atomicAdd(&cursor[dst[e]], 1);
        edge_ids[p] = e;
    }
}

// ---------- K7: pull aggregation + ReLU ----------
// block 256 = 4 waves; wave handles one dst node; lane owns 2 columns.
__global__ __launch_bounds__(256) void k_aggregate(
    const uint16_t* __restrict__ hr, const int* __restrict__ offsets,
    const int* __restrict__ edge_ids, const int* __restrict__ src,
    const int* __restrict__ rel, const float* __restrict__ norm,
    float* __restrict__ out, int N)
{
    const int wid  = __builtin_amdgcn_readfirstlane(threadIdx.x >> 6);
    const int lane = threadIdx.x & 63;
    const int n = blockIdx.x * 4 + wid;
    if (n >= N) return;

    const int start = offsets[n];
    const int end   = offsets[n + 1];
    const int c = lane * 2;

    float a0 = 0.f, a1 = 0.f;

    int idx = start;
    for (; idx + 1 < end; idx += 2) {
        int e0 = edge_ids[idx];
        int e1 = edge_ids[idx + 1];
        int s0 = src[e0], s1 = src[e1];
        int r0 = rel[e0], r1 = rel[e1];
        float w0 = norm[e0], w1 = norm[e1];
        uint32_t v0 = *reinterpret_cast<const uint32_t*>(&hr[((size_t)r0 * N + s0) * NFEAT + c]);
        uint32_t v1 = *reinterpret_cast<const uint32_t*>(&hr[((size_t)r1 * N + s1) * NFEAT + c]);
        a0 += w0 * bf2f(v0 & 0xFFFFu);
        a1 += w0 * bf2f(v0 >> 16);
        a0 += w1 * bf2f(v1 & 0xFFFFu);
        a1 += w1 * bf2f(v1 >> 16);
    }
    if (idx < end) {
        int e0 = edge_ids[idx];
        int s0 = src[e0];
        int r0 = rel[e0];
        float w0 = norm[e0];
        uint32_t v0 = *reinterpret_cast<const uint32_t*>(&hr[((size_t)r0 * N + s0) * NFEAT + c]);
        a0 += w0 * bf2f(v0 & 0xFFFFu);
        a1 += w0 * bf2f(v0 >> 16);
    }

    float2 o;
    o.x = fmaxf(a0, 0.f);
    o.y = fmaxf(a1, 0.f);
    *reinterpret_cast<float2*>(&out[(size_t)n * NFEAT + c]) = o;
}

// ---------- launch ----------
extern "C" void kernel_launch(void* const* d_in, const int* in_sizes, int n_in,
                              void* d_out, int out_size, void* d_ws, size_t ws_size,
                              hipStream_t stream)
{
    const float* feat = (const float*)d_in[0];
    const float* W    = (const float*)d_in[1];
    const float* norm = (const float*)d_in[2];
    const int*   src  = (const int*)d_in[3];
    const int*   dst  = (const int*)d_in[4];
    const int*   rel  = (const int*)d_in[5];
    float* out = (float*)d_out;

    const int N = in_sizes[0] / NFEAT;   // 50000
    const int E = in_sizes[2];           // 800000
    const int NB = (N + 255) / 256;      // 196

    // workspace layout (aligned to 64B)
    char* ws = (char*)d_ws;
    size_t off = 0;
    auto alloc = [&](size_t bytes) -> char* {
        char* p = ws + off;
        off += (bytes + 63) & ~(size_t)63;
        return p;
    };
    uint16_t* hr      = (uint16_t*)alloc((size_t)NREL * N * NFEAT * 2);
    int* counts       = (int*)alloc((size_t)N * 4);
    int* offsets      = (int*)alloc((size_t)(N + 1) * 4);
    int* cursor       = (int*)alloc((size_t)N * 4);
    int* blocksum     = (int*)alloc((size_t)NB * 4);
    int* blockoff     = (int*)alloc((size_t)NB * 4);
    int* edge_ids     = (int*)alloc((size_t)E * 4);
    (void)ws_size;

    // K0: zero counters
    k_zero<<<NB, 256, 0, stream>>>(counts, N);
    // K1: grouped GEMM -> hr (bf16)
    dim3 ggrid((N + 63) / 64, NREL);
    k_gemm<<<ggrid, 256, 0, stream>>>(feat, W, hr, N);
    // K2: histogram over dst
    k_hist<<<(E + 255) / 256, 256, 0, stream>>>(dst, counts, E);
    // K3..K5: exclusive scan -> offsets, cursor
    k_block_reduce<<<NB, 256, 0, stream>>>(counts, blocksum, N);
    k_scan_partials<<<1, 256, 0, stream>>>(blocksum, blockoff, NB);
    k_offsets<<<NB, 256, 0, stream>>>(counts, blockoff, offsets, cursor, N, E);
    // K6: fill CSR
    k_fill<<<(E + 255) / 256, 256, 0, stream>>>(dst, cursor, edge_ids, E);
    // K7: pull aggregation + ReLU
    k_aggregate<<<(N + 3) / 4, 256, 0, stream>>>(hr, offsets, edge_ids, src, rel, norm, out, N);
}

// Round 2
// 169.771 us; speedup vs baseline: 1.7161x; 1.7161x over previous
//
#include <hip/hip_runtime.h>
#include <stdint.h>

#define NFEAT  128
#define NREL   3

typedef short short8 __attribute__((ext_vector_type(8)));
typedef float f32x4  __attribute__((ext_vector_type(4)));

// ---------- helpers ----------
__device__ __forceinline__ uint32_t f2bf(float x) {
    uint32_t u = __builtin_bit_cast(uint32_t, x);
    uint32_t r = (u + 0x7FFFu + ((u >> 16) & 1u)) >> 16;  // RNE
    return r & 0xFFFFu;
}
__device__ __forceinline__ float bf2f(uint32_t b) {
    uint32_t u = b << 16;
    return __builtin_bit_cast(float, u);
}

// ---------- K0: zero the histogram counters ----------
__global__ void k_zero(int* __restrict__ p, int n) {
    int i = blockIdx.x * 256 + threadIdx.x;
    if (i < n) p[i] = 0;
}

// ---------- K_prep_w: W[r][k][o] fp32 -> Wt[r][o][k] bf16 ----------
__global__ void k_prep_w(const float* __restrict__ W, uint16_t* __restrict__ Wt) {
    int tid = blockIdx.x * 256 + threadIdx.x;
    if (tid >= NREL * NFEAT * NFEAT) return;
    int o = tid & 127;
    int k = (tid >> 7) & 127;
    int r = tid >> 14;
    float v = W[(size_t)r * NFEAT * NFEAT + (size_t)k * NFEAT + o];
    Wt[(size_t)r * NFEAT * NFEAT + (size_t)o * NFEAT + k] = (uint16_t)f2bf(v);
}

// ---------- K1: grouped GEMM hr[r] = feat @ W[r] via bf16 MFMA ----------
// BM=64, BN=128 (full), K=128. 256 threads = 4 waves; wave w owns rows w*16..+15.
// LDS tiles XOR-swizzled (byte ^= (row&7)<<4) so ds_read_b128 is conflict-free.
__global__ __launch_bounds__(256) void k_gemm_mfma(
    const float* __restrict__ feat, const uint16_t* __restrict__ Wt,
    uint16_t* __restrict__ hr, int N)
{
    __shared__ uint16_t ldsA[64 * 128];    // 16 KB, [row][k] swizzled
    __shared__ uint16_t ldsB[128 * 128];   // 32 KB, [ocol][k] swizzled

    const int t    = threadIdx.x;
    const int lane = t & 63;
    const int w    = t >> 6;
    const int n0   = blockIdx.x * 64;

    // ---- stage A (fp32 -> bf16, swizzled) ----
    {
        const int kq = t & 15;     // 8-element chunk along k
        const int rq = t >> 4;     // 0..15
        #pragma unroll
        for (int rr = 0; rr < 4; rr++) {
            const int row = rr * 16 + rq;
            const int n = n0 + row;
            uint4 pk = make_uint4(0, 0, 0, 0);
            if (n < N) {
                const float4* p = reinterpret_cast<const float4*>(&feat[(size_t)n * NFEAT + kq * 8]);
                float4 v0 = p[0], v1 = p[1];
                pk.x = f2bf(v0.x) | (f2bf(v0.y) << 16);
                pk.y = f2bf(v0.z) | (f2bf(v0.w) << 16);
                pk.z = f2bf(v1.x) | (f2bf(v1.y) << 16);
                pk.w = f2bf(v1.z) | (f2bf(v1.w) << 16);
            }
            uint32_t byte = (uint32_t)(row * 256 + kq * 16) ^ ((uint32_t)(row & 7) << 4);
            *reinterpret_cast<uint4*>(reinterpret_cast<char*>(ldsA) + byte) = pk;
        }
    }

    const int rowf = lane & 15;   // fragment row (A) / out-col (B,D)
    const int kb   = lane >> 4;   // 0..3

    for (int r = 0; r < NREL; r++) {
        // ---- stage B = Wt[r] (bf16, swizzled) ----
        {
            const int kq = t & 15;
            const int rq = t >> 4;
            const uint16_t* Wr = Wt + (size_t)r * NFEAT * NFEAT;
            #pragma unroll
            for (int rr = 0; rr < 8; rr++) {
                const int row = rr * 16 + rq;
                uint4 v = *reinterpret_cast<const uint4*>(&Wr[(size_t)row * NFEAT + kq * 8]);
                uint32_t byte = (uint32_t)(row * 256 + kq * 16) ^ ((uint32_t)(row & 7) << 4);
                *reinterpret_cast<uint4*>(reinterpret_cast<char*>(ldsB) + byte) = v;
            }
        }
        __syncthreads();

        // ---- A fragments (reused across all 8 col-frags) ----
        short8 a[4];
        {
            const int row = w * 16 + rowf;
            #pragma unroll
            for (int ks = 0; ks < 4; ks++) {
                uint32_t byte = (uint32_t)(row * 256 + ks * 64 + kb * 16) ^ ((uint32_t)(row & 7) << 4);
                a[ks] = *reinterpret_cast<const short8*>(reinterpret_cast<char*>(ldsA) + byte);
            }
        }

        f32x4 acc[8];
        #pragma unroll
        for (int cf = 0; cf < 8; cf++) acc[cf] = (f32x4){0.f, 0.f, 0.f, 0.f};

        #pragma unroll
        for (int cf = 0; cf < 8; cf++) {
            const int col = cf * 16 + rowf;
            #pragma unroll
            for (int ks = 0; ks < 4; ks++) {
                uint32_t byte = (uint32_t)(col * 256 + ks * 64 + kb * 16) ^ ((uint32_t)(col & 7) << 4);
                short8 b = *reinterpret_cast<const short8*>(reinterpret_cast<char*>(ldsB) + byte);
                acc[cf] = __builtin_amdgcn_mfma_f32_16x16x32_bf16(a[ks], b, acc[cf], 0, 0, 0);
            }
        }

        // ---- C write: D layout col=lane&15, row=(lane>>4)*4+j ----
        #pragma unroll
        for (int cf = 0; cf < 8; cf++) {
            #pragma unroll
            for (int j = 0; j < 4; j++) {
                const int n = n0 + w * 16 + kb * 4 + j;
                if (n < N)
                    hr[((size_t)r * N + n) * NFEAT + cf * 16 + rowf] = (uint16_t)f2bf(acc[cf][j]);
            }
        }
        __syncthreads();  // before next relation overwrites ldsB
    }
}

// ---------- K2: histogram of dst ----------
__global__ void k_hist(const int* __restrict__ dst, int* __restrict__ counts, int E) {
    int e = blockIdx.x * 256 + threadIdx.x;
    if (e < E) atomicAdd(&counts[dst[e]], 1);
}

// ---------- K3: per-block reduce of counts ----------
__global__ void k_block_reduce(const int* __restrict__ counts, int* __restrict__ blocksum, int n) {
    __shared__ int sm[256];
    int t = threadIdx.x;
    int i = blockIdx.x * 256 + t;
    sm[t] = (i < n) ? counts[i] : 0;
    __syncthreads();
    for (int s = 128; s > 0; s >>= 1) {
        if (t < s) sm[t] += sm[t + s];
        __syncthreads();
    }
    if (t == 0) blocksum[blockIdx.x] = sm[0];
}

// ---------- K4: single-block exclusive scan of block sums ----------
__global__ void k_scan_partials(const int* __restrict__ blocksum, int* __restrict__ blockoff, int nb) {
    __shared__ int sm[256];
    int t = threadIdx.x;
    int v = (t < nb) ? blocksum[t] : 0;
    sm[t] = v;
    __syncthreads();
    for (int s = 1; s < 256; s <<= 1) {
        int add = (t >= s) ? sm[t - s] : 0;
        __syncthreads();
        sm[t] += add;
        __syncthreads();
    }
    if (t < nb) blockoff[t] = sm[t] - v;
}

// ---------- K5: write offsets (exclusive scan) + cursor copy ----------
__global__ void k_offsets(const int* __restrict__ counts, const int* __restrict__ blockoff,
                          int* __restrict__ offsets, int* __restrict__ cursor, int n, int total) {
    __shared__ int sm[256];
    int t = threadIdx.x;
    int i = blockIdx.x * 256 + t;
    int v = (i < n) ? counts[i] : 0;
    sm[t] = v;
    __syncthreads();
    for (int s = 1; s < 256; s <<= 1) {
        int add = (t >= s) ? sm[t - s] : 0;
        __syncthreads();
        sm[t] += add;
        __syncthreads();
    }
    int excl = sm[t] - v + blockoff[blockIdx.x];
    if (i < n) { offsets[i] = excl; cursor[i] = excl; }
    if (i == 0) offsets[n] = total;
}

// ---------- K6: fill CSR with packed metadata (src|rel<<16, norm) ----------
__global__ void k_fill(const int* __restrict__ dst, const int* __restrict__ src,
                       const int* __restrict__ rel, const float* __restrict__ norm,
                       int* __restrict__ cursor, uint2* __restrict__ meta, int E) {
    int e = blockIdx.x * 256 + threadIdx.x;
    if (e < E) {
        int p = atomicAdd(&cursor[dst[e]], 1);
        uint32_t packed = (uint32_t)src[e] | ((uint32_t)rel[e] << 16);
        meta[p] = make_uint2(packed, __builtin_bit_cast(uint32_t, norm[e]));
    }
}

// ---------- K7: pull aggregation + ReLU ----------
// wave per dst node; lane owns 2 columns (one 4B bf16x2 load = full 256B row/wave).
__global__ __launch_bounds__(256) void k_aggregate(
    const uint16_t* __restrict__ hr, const int* __restrict__ offsets,
    const uint2* __restrict__ meta, float* __restrict__ out, int N)
{
    const int wid  = threadIdx.x >> 6;
    const int lane = threadIdx.x & 63;
    const int n = blockIdx.x * 4 + wid;
    if (n >= N) return;

    const int start = offsets[n];
    const int end   = offsets[n + 1];
    const int c = lane * 2;

    float a0 = 0.f, a1 = 0.f;
    int idx = start;

    for (; idx + 3 < end; idx += 4) {
        uint2 m0 = meta[idx];
        uint2 m1 = meta[idx + 1];
        uint2 m2 = meta[idx + 2];
        uint2 m3 = meta[idx + 3];
        const uint32_t* p0 = reinterpret_cast<const uint32_t*>(
            &hr[((size_t)(m0.x >> 16) * N + (m0.x & 0xFFFFu)) * NFEAT + c]);
        const uint32_t* p1 = reinterpret_cast<const uint32_t*>(
            &hr[((size_t)(m1.x >> 16) * N + (m1.x & 0xFFFFu)) * NFEAT + c]);
        const uint32_t* p2 = reinterpret_cast<const uint32_t*>(
            &hr[((size_t)(m2.x >> 16) * N + (m2.x & 0xFFFFu)) * NFEAT + c]);
        const uint32_t* p3 = reinterpret_cast<const uint32_t*>(
            &hr[((size_t)(m3.x >> 16) * N + (m3.x & 0xFFFFu)) * NFEAT + c]);
        uint32_t v0 = *p0, v1 = *p1, v2 = *p2, v3 = *p3;
        float w0 = __builtin_bit_cast(float, m0.y);
        float w1 = __builtin_bit_cast(float, m1.y);
        float w2 = __builtin_bit_cast(float, m2.y);
        float w3 = __builtin_bit_cast(float, m3.y);
        a0 += w0 * bf2f(v0 & 0xFFFFu); a1 += w0 * bf2f(v0 >> 16);
        a0 += w1 * bf2f(v1 & 0xFFFFu); a1 += w1 * bf2f(v1 >> 16);
        a0 += w2 * bf2f(v2 & 0xFFFFu); a1 += w2 * bf2f(v2 >> 16);
        a0 += w3 * bf2f(v3 & 0xFFFFu); a1 += w3 * bf2f(v3 >> 16);
    }
    for (; idx < end; idx++) {
        uint2 m = meta[idx];
        uint32_t v = *reinterpret_cast<const uint32_t*>(
            &hr[((size_t)(m.x >> 16) * N + (m.x & 0xFFFFu)) * NFEAT + c]);
        float wgt = __builtin_bit_cast(float, m.y);
        a0 += wgt * bf2f(v & 0xFFFFu);
        a1 += wgt * bf2f(v >> 16);
    }

    float2 o;
    o.x = fmaxf(a0, 0.f);
    o.y = fmaxf(a1, 0.f);
    *reinterpret_cast<float2*>(&out[(size_t)n * NFEAT + c]) = o;
}

// ---------- launch ----------
extern "C" void kernel_launch(void* const* d_in, const int* in_sizes, int n_in,
                              void* d_out, int out_size, void* d_ws, size_t ws_size,
                              hipStream_t stream)
{
    const float* feat = (const float*)d_in[0];
    const float* W    = (const float*)d_in[1];
    const float* norm = (const float*)d_in[2];
    const int*   src  = (const int*)d_in[3];
    const int*   dst  = (const int*)d_in[4];
    const int*   rel  = (const int*)d_in[5];
    float* out = (float*)d_out;

    const int N = in_sizes[0] / NFEAT;   // 50000
    const int E = in_sizes[2];           // 800000
    const int NB = (N + 255) / 256;      // 196

    char* ws = (char*)d_ws;
    size_t off = 0;
    auto alloc = [&](size_t bytes) -> char* {
        char* p = ws + off;
        off += (bytes + 63) & ~(size_t)63;
        return p;
    };
    uint16_t* hr   = (uint16_t*)alloc((size_t)NREL * N * NFEAT * 2);  // 38.4 MB
    uint16_t* Wt   = (uint16_t*)alloc((size_t)NREL * NFEAT * NFEAT * 2);
    int* counts    = (int*)alloc((size_t)N * 4);
    int* offsets   = (int*)alloc((size_t)(N + 1) * 4);
    int* cursor    = (int*)alloc((size_t)N * 4);
    int* blocksum  = (int*)alloc((size_t)NB * 4);
    int* blockoff  = (int*)alloc((size_t)NB * 4);
    uint2* meta    = (uint2*)alloc((size_t)E * 8);                    // 6.4 MB
    (void)ws_size;

    k_zero<<<NB, 256, 0, stream>>>(counts, N);
    k_prep_w<<<(NREL * NFEAT * NFEAT + 255) / 256, 256, 0, stream>>>(W, Wt);
    k_gemm_mfma<<<(N + 63) / 64, 256, 0, stream>>>(feat, Wt, hr, N);
    k_hist<<<(E + 255) / 256, 256, 0, stream>>>(dst, counts, E);
    k_block_reduce<<<NB, 256, 0, stream>>>(counts, blocksum, N);
    k_scan_partials<<<1, 256, 0, stream>>>(blocksum, blockoff, NB);
    k_offsets<<<NB, 256, 0, stream>>>(counts, blockoff, offsets, cursor, N, E);
    k_fill<<<(E + 255) / 256, 256, 0, stream>>>(dst, src, rel, norm, cursor, meta, E);
    k_aggregate<<<(N + 3) / 4, 256, 0, stream>>>(hr, offsets, meta, out, N);
}

// Round 3
// 113.676 us; speedup vs baseline: 2.5629x; 1.4935x over previous
//
#include <hip/hip_runtime.h>
#include <stdint.h>

#define NFEAT  128
#define NREL   3

typedef short short8 __attribute__((ext_vector_type(8)));
typedef float f32x4  __attribute__((ext_vector_type(4)));

// ---------- helpers ----------
__device__ __forceinline__ uint32_t f2bf(float x) {
    uint32_t u = __builtin_bit_cast(uint32_t, x);
    uint32_t r = (u + 0x7FFFu + ((u >> 16) & 1u)) >> 16;  // RNE
    return r & 0xFFFFu;
}
__device__ __forceinline__ float bf2f(uint32_t b) {
    uint32_t u = b << 16;
    return __builtin_bit_cast(float, u);
}

// ---------- K0: zero small counter array ----------
__global__ void k_zero(int* __restrict__ p, int n) {
    int i = blockIdx.x * 256 + threadIdx.x;
    if (i < n) p[i] = 0;
}

// ---------- K_prep_w: W[r][k][o] fp32 -> Wt[r][o][k] bf16 ----------
__global__ void k_prep_w(const float* __restrict__ W, uint16_t* __restrict__ Wt) {
    int tid = blockIdx.x * 256 + threadIdx.x;
    if (tid >= NREL * NFEAT * NFEAT) return;
    int o = tid & 127;
    int k = (tid >> 7) & 127;
    int r = tid >> 14;
    float v = W[(size_t)r * NFEAT * NFEAT + (size_t)k * NFEAT + o];
    Wt[(size_t)r * NFEAT * NFEAT + (size_t)o * NFEAT + k] = (uint16_t)f2bf(v);
}

// ---------- K1: grouped GEMM hr[r] = feat @ W[r] via bf16 MFMA ----------
__global__ __launch_bounds__(256) void k_gemm_mfma(
    const float* __restrict__ feat, const uint16_t* __restrict__ Wt,
    uint16_t* __restrict__ hr, int N)
{
    __shared__ uint16_t ldsA[64 * 128];    // 16 KB, [row][k] swizzled
    __shared__ uint16_t ldsB[128 * 128];   // 32 KB, [ocol][k] swizzled

    const int t    = threadIdx.x;
    const int lane = t & 63;
    const int w    = t >> 6;
    const int n0   = blockIdx.x * 64;

    // ---- stage A (fp32 -> bf16, swizzled) ----
    {
        const int kq = t & 15;
        const int rq = t >> 4;
        #pragma unroll
        for (int rr = 0; rr < 4; rr++) {
            const int row = rr * 16 + rq;
            const int n = n0 + row;
            uint4 pk = make_uint4(0, 0, 0, 0);
            if (n < N) {
                const float4* p = reinterpret_cast<const float4*>(&feat[(size_t)n * NFEAT + kq * 8]);
                float4 v0 = p[0], v1 = p[1];
                pk.x = f2bf(v0.x) | (f2bf(v0.y) << 16);
                pk.y = f2bf(v0.z) | (f2bf(v0.w) << 16);
                pk.z = f2bf(v1.x) | (f2bf(v1.y) << 16);
                pk.w = f2bf(v1.z) | (f2bf(v1.w) << 16);
            }
            uint32_t byte = (uint32_t)(row * 256 + kq * 16) ^ ((uint32_t)(row & 7) << 4);
            *reinterpret_cast<uint4*>(reinterpret_cast<char*>(ldsA) + byte) = pk;
        }
    }

    const int rowf = lane & 15;
    const int kb   = lane >> 4;

    for (int r = 0; r < NREL; r++) {
        {
            const int kq = t & 15;
            const int rq = t >> 4;
            const uint16_t* Wr = Wt + (size_t)r * NFEAT * NFEAT;
            #pragma unroll
            for (int rr = 0; rr < 8; rr++) {
                const int row = rr * 16 + rq;
                uint4 v = *reinterpret_cast<const uint4*>(&Wr[(size_t)row * NFEAT + kq * 8]);
                uint32_t byte = (uint32_t)(row * 256 + kq * 16) ^ ((uint32_t)(row & 7) << 4);
                *reinterpret_cast<uint4*>(reinterpret_cast<char*>(ldsB) + byte) = v;
            }
        }
        __syncthreads();

        short8 a[4];
        {
            const int row = w * 16 + rowf;
            #pragma unroll
            for (int ks = 0; ks < 4; ks++) {
                uint32_t byte = (uint32_t)(row * 256 + ks * 64 + kb * 16) ^ ((uint32_t)(row & 7) << 4);
                a[ks] = *reinterpret_cast<const short8*>(reinterpret_cast<char*>(ldsA) + byte);
            }
        }

        f32x4 acc[8];
        #pragma unroll
        for (int cf = 0; cf < 8; cf++) acc[cf] = (f32x4){0.f, 0.f, 0.f, 0.f};

        #pragma unroll
        for (int cf = 0; cf < 8; cf++) {
            const int col = cf * 16 + rowf;
            #pragma unroll
            for (int ks = 0; ks < 4; ks++) {
                uint32_t byte = (uint32_t)(col * 256 + ks * 64 + kb * 16) ^ ((uint32_t)(col & 7) << 4);
                short8 b = *reinterpret_cast<const short8*>(reinterpret_cast<char*>(ldsB) + byte);
                acc[cf] = __builtin_amdgcn_mfma_f32_16x16x32_bf16(a[ks], b, acc[cf], 0, 0, 0);
            }
        }

        #pragma unroll
        for (int cf = 0; cf < 8; cf++) {
            #pragma unroll
            for (int j = 0; j < 4; j++) {
                const int n = n0 + w * 16 + kb * 4 + j;
                if (n < N)
                    hr[((size_t)r * N + n) * NFEAT + cf * 16 + rowf] = (uint16_t)f2bf(acc[cf][j]);
            }
        }
        __syncthreads();
    }
}

// ---------- K2: per-bin histogram (bin = dst >> 8), LDS pre-aggregated ----------
__global__ __launch_bounds__(256) void k_binhist(
    const int* __restrict__ dst, int* __restrict__ bincnt, int E)
{
    __shared__ int h[256];
    const int t = threadIdx.x;
    h[t] = 0;
    __syncthreads();
    int e = blockIdx.x * 2048 + t;
    #pragma unroll
    for (int j = 0; j < 8; j++, e += 256)
        if (e < E) atomicAdd(&h[dst[e] >> 8], 1);
    __syncthreads();
    if (h[t]) atomicAdd(&bincnt[t], h[t]);
}

// ---------- K3: single-block scan of bin counts ----------
__global__ __launch_bounds__(256) void k_binscan(
    const int* __restrict__ bincnt, int* __restrict__ binoff,
    int* __restrict__ bincursor, int* __restrict__ offsets,
    int N, int E, int nbins)
{
    __shared__ int sm[256];
    const int t = threadIdx.x;
    int v = (t < nbins) ? bincnt[t] : 0;
    sm[t] = v;
    __syncthreads();
    for (int s = 1; s < 256; s <<= 1) {
        int a = (t >= s) ? sm[t - s] : 0;
        __syncthreads();
        sm[t] += a;
        __syncthreads();
    }
    int excl = sm[t] - v;
    if (t < nbins) { binoff[t] = excl; bincursor[t] = excl; }
    if (t == 0) { binoff[nbins] = E; offsets[N] = E; }
}

// ---------- K4: bin-grouped fill of packed records ----------
// record: (src | rel<<16 | dstlocal<<18, norm)
__global__ __launch_bounds__(256) void k_binfill(
    const int* __restrict__ dst, const int* __restrict__ src,
    const int* __restrict__ rel, const float* __restrict__ norm,
    int* __restrict__ bincursor, uint2* __restrict__ binbuf, int E)
{
    __shared__ int hist[256];
    __shared__ int base[256];
    __shared__ int rank[256];
    const int t = threadIdx.x;
    const int e0 = blockIdx.x * 2048;

    hist[t] = 0;
    __syncthreads();

    int myBin[8], myDl[8];
    #pragma unroll
    for (int j = 0; j < 8; j++) {
        int e = e0 + t + j * 256;
        int b = -1, dl = 0;
        if (e < E) {
            int d = dst[e];
            b = d >> 8;
            dl = d & 255;
            atomicAdd(&hist[b], 1);
        }
        myBin[j] = b;
        myDl[j] = dl;
    }
    __syncthreads();

    int h = hist[t];
    if (h > 0) base[t] = atomicAdd(&bincursor[t], h);
    rank[t] = 0;
    __syncthreads();

    #pragma unroll
    for (int j = 0; j < 8; j++) {
        int e = e0 + t + j * 256;
        if (myBin[j] >= 0) {
            int p = base[myBin[j]] + atomicAdd(&rank[myBin[j]], 1);
            uint32_t px = (uint32_t)src[e] | ((uint32_t)rel[e] << 16) | ((uint32_t)myDl[j] << 18);
            binbuf[p] = make_uint2(px, __builtin_bit_cast(uint32_t, norm[e]));
        }
    }
}

// ---------- K5: per-bin dst-sort -> CSR offsets + sorted meta ----------
__global__ __launch_bounds__(256) void k_binsort(
    const uint2* __restrict__ binbuf, const int* __restrict__ binoff,
    uint2* __restrict__ meta, int* __restrict__ offsets, int N)
{
    __shared__ int sm[256];
    __shared__ int cur[256];
    const int b = blockIdx.x;
    const int t = threadIdx.x;
    const int base = binoff[b];
    const int cnt  = binoff[b + 1] - base;

    sm[t] = 0;
    __syncthreads();
    for (int i = t; i < cnt; i += 256) {
        uint2 r = binbuf[base + i];
        atomicAdd(&sm[(r.x >> 18) & 255], 1);
    }
    __syncthreads();
    int v = sm[t];
    __syncthreads();
    sm[t] = v;
    __syncthreads();
    for (int s = 1; s < 256; s <<= 1) {
        int a = (t >= s) ? sm[t - s] : 0;
        __syncthreads();
        sm[t] += a;
        __syncthreads();
    }
    int excl = sm[t] - v;
    int n = b * 256 + t;
    if (n < N) offsets[n] = base + excl;
    cur[t] = excl;
    __syncthreads();

    for (int i = t; i < cnt; i += 256) {
        uint2 r = binbuf[base + i];
        int dl = (r.x >> 18) & 255;
        int p = atomicAdd(&cur[dl], 1);
        meta[base + p] = make_uint2(r.x & 0x3FFFFu, r.y);
    }
}

// ---------- K6: pull aggregation + ReLU ----------
__global__ __launch_bounds__(256) void k_aggregate(
    const uint16_t* __restrict__ hr, const int* __restrict__ offsets,
    const uint2* __restrict__ meta, float* __restrict__ out, int N)
{
    const int wid  = threadIdx.x >> 6;
    const int lane = threadIdx.x & 63;
    const int n = blockIdx.x * 4 + wid;
    if (n >= N) return;

    const int start = offsets[n];
    const int end   = offsets[n + 1];
    const int c = lane * 2;

    float a0 = 0.f, a1 = 0.f;
    int idx = start;

    for (; idx + 3 < end; idx += 4) {
        uint2 m0 = meta[idx];
        uint2 m1 = meta[idx + 1];
        uint2 m2 = meta[idx + 2];
        uint2 m3 = meta[idx + 3];
        const uint32_t* p0 = reinterpret_cast<const uint32_t*>(
            &hr[((size_t)(m0.x >> 16) * N + (m0.x & 0xFFFFu)) * NFEAT + c]);
        const uint32_t* p1 = reinterpret_cast<const uint32_t*>(
            &hr[((size_t)(m1.x >> 16) * N + (m1.x & 0xFFFFu)) * NFEAT + c]);
        const uint32_t* p2 = reinterpret_cast<const uint32_t*>(
            &hr[((size_t)(m2.x >> 16) * N + (m2.x & 0xFFFFu)) * NFEAT + c]);
        const uint32_t* p3 = reinterpret_cast<const uint32_t*>(
            &hr[((size_t)(m3.x >> 16) * N + (m3.x & 0xFFFFu)) * NFEAT + c]);
        uint32_t v0 = *p0, v1 = *p1, v2 = *p2, v3 = *p3;
        float w0 = __builtin_bit_cast(float, m0.y);
        float w1 = __builtin_bit_cast(float, m1.y);
        float w2 = __builtin_bit_cast(float, m2.y);
        float w3 = __builtin_bit_cast(float, m3.y);
        a0 += w0 * bf2f(v0 & 0xFFFFu); a1 += w0 * bf2f(v0 >> 16);
        a0 += w1 * bf2f(v1 & 0xFFFFu); a1 += w1 * bf2f(v1 >> 16);
        a0 += w2 * bf2f(v2 & 0xFFFFu); a1 += w2 * bf2f(v2 >> 16);
        a0 += w3 * bf2f(v3 & 0xFFFFu); a1 += w3 * bf2f(v3 >> 16);
    }
    for (; idx < end; idx++) {
        uint2 m = meta[idx];
        uint32_t v = *reinterpret_cast<const uint32_t*>(
            &hr[((size_t)(m.x >> 16) * N + (m.x & 0xFFFFu)) * NFEAT + c]);
        float wgt = __builtin_bit_cast(float, m.y);
        a0 += wgt * bf2f(v & 0xFFFFu);
        a1 += wgt * bf2f(v >> 16);
    }

    float2 o;
    o.x = fmaxf(a0, 0.f);
    o.y = fmaxf(a1, 0.f);
    *reinterpret_cast<float2*>(&out[(size_t)n * NFEAT + c]) = o;
}

// ---------- launch ----------
extern "C" void kernel_launch(void* const* d_in, const int* in_sizes, int n_in,
                              void* d_out, int out_size, void* d_ws, size_t ws_size,
                              hipStream_t stream)
{
    const float* feat = (const float*)d_in[0];
    const float* W    = (const float*)d_in[1];
    const float* norm = (const float*)d_in[2];
    const int*   src  = (const int*)d_in[3];
    const int*   dst  = (const int*)d_in[4];
    const int*   rel  = (const int*)d_in[5];
    float* out = (float*)d_out;

    const int N = in_sizes[0] / NFEAT;      // 50000
    const int E = in_sizes[2];              // 800000
    const int NBINS = (N + 255) / 256;      // 196

    char* ws = (char*)d_ws;
    size_t off = 0;
    auto alloc = [&](size_t bytes) -> char* {
        char* p = ws + off;
        off += (bytes + 63) & ~(size_t)63;
        return p;
    };
    uint16_t* hr    = (uint16_t*)alloc((size_t)NREL * N * NFEAT * 2);  // 38.4 MB
    uint16_t* Wt    = (uint16_t*)alloc((size_t)NREL * NFEAT * NFEAT * 2);
    int* bincnt     = (int*)alloc(256 * 4);
    int* binoff     = (int*)alloc(257 * 4);
    int* bincursor  = (int*)alloc(256 * 4);
    int* offsets    = (int*)alloc((size_t)(N + 1) * 4);
    uint2* meta     = (uint2*)alloc((size_t)E * 8);                    // 6.4 MB
    (void)ws_size;

    // binbuf (6.4 MB) aliases d_out (25.6 MB): fully written by k_binfill before
    // k_binsort reads it; k_aggregate fully overwrites out afterwards.
    uint2* binbuf = (uint2*)d_out;

    k_zero<<<1, 256, 0, stream>>>(bincnt, 256);
    k_prep_w<<<(NREL * NFEAT * NFEAT + 255) / 256, 256, 0, stream>>>(W, Wt);
    k_gemm_mfma<<<(N + 63) / 64, 256, 0, stream>>>(feat, Wt, hr, N);
    k_binhist<<<(E + 2047) / 2048, 256, 0, stream>>>(dst, bincnt, E);
    k_binscan<<<1, 256, 0, stream>>>(bincnt, binoff, bincursor, offsets, N, E, NBINS);
    k_binfill<<<(E + 2047) / 2048, 256, 0, stream>>>(dst, src, rel, norm, bincursor, binbuf, E);
    k_binsort<<<NBINS, 256, 0, stream>>>(binbuf, binoff, meta, offsets, N);
    k_aggregate<<<(N + 3) / 4, 256, 0, stream>>>(hr, offsets, meta, out, N);
}